// Round 23
// baseline (458.597 us; speedup 1.0000x reference)
//
#include <hip/hip_runtime.h>

#define IN_DIM  512
#define HID_DIM 256
#define OUT_DIM 64
#define KPROP   5
#define ALPHA   0.1f

#define BKT_SHIFT 9            // 512 dst nodes per bucket
#define PART_EPB  8192         // edges per partition block

typedef short short8v __attribute__((ext_vector_type(8)));
typedef float f32x4   __attribute__((ext_vector_type(4)));
typedef float f32x2   __attribute__((ext_vector_type(2)));

__device__ __forceinline__ unsigned short f2bf(float f) {
    unsigned u = __builtin_bit_cast(unsigned, f);
    unsigned r = (u + 0x7FFFu + ((u >> 16) & 1u)) >> 16;
    return (unsigned short)r;
}
__device__ __forceinline__ float bflo(unsigned v) { return __builtin_bit_cast(float, v << 16); }
__device__ __forceinline__ float bfhi(unsigned v) { return __builtin_bit_cast(float, v & 0xffff0000u); }

// ---------------- bucket-level edge count ----------------
__global__ __launch_bounds__(256) void bucket_count_kernel(const int* __restrict__ ei, int E,
                                                           int* __restrict__ bucketCnt) {
    __shared__ int hist[256];
    int t = threadIdx.x;
    hist[t] = 0;
    __syncthreads();
    int e0 = blockIdx.x * PART_EPB;
#pragma unroll 4
    for (int i = 0; i < PART_EPB / 256; ++i) {
        int e = e0 + i * 256 + t;
        if (e < E) atomicAdd(&hist[ei[E + e] >> BKT_SHIFT], 1);
    }
    __syncthreads();
    if (hist[t] > 0) atomicAdd(&bucketCnt[t], hist[t]);
}

// ---------------- bucket scan (1 block) ----------------
__global__ __launch_bounds__(256) void bucket_scan_kernel(const int* __restrict__ bucketCnt,
                                                          int* __restrict__ bucketBase,
                                                          int* __restrict__ bucketFill,
                                                          int* __restrict__ indptr,
                                                          int E, int N) {
    __shared__ int sm[256];
    int t = threadIdx.x;
    int v = bucketCnt[t];
    sm[t] = v;
    __syncthreads();
    for (int off = 1; off < 256; off <<= 1) {
        int add = 0;
        if (t >= off) add = sm[t - off];
        __syncthreads();
        if (t >= off) sm[t] += add;
        __syncthreads();
    }
    int base = sm[t] - v;
    bucketBase[t] = base;
    bucketFill[t] = base;
    if (t == 0) indptr[N] = E;
}

// ---------------- partition; packed = (dst&511)<<17 | src ----------------
__global__ __launch_bounds__(256) void partition_kernel(const int* __restrict__ ei, int E,
                                                        int* __restrict__ bucketFill,
                                                        int* __restrict__ packed) {
    __shared__ int hist[256];
    __shared__ int base[256];
    int t = threadIdx.x;
    int e0 = blockIdx.x * PART_EPB;
    hist[t] = 0;
    __syncthreads();
#pragma unroll 4
    for (int i = 0; i < PART_EPB / 256; ++i) {
        int e = e0 + i * 256 + t;
        if (e < E) atomicAdd(&hist[ei[E + e] >> BKT_SHIFT], 1);
    }
    __syncthreads();
    int cnt = hist[t];
    if (cnt > 0) base[t] = atomicAdd(&bucketFill[t], cnt);
    __syncthreads();
#pragma unroll 4
    for (int i = 0; i < PART_EPB / 256; ++i) {
        int e = e0 + i * 256 + t;
        if (e < E) {
            int dst = ei[E + e];
            int src = ei[e];
            int b = dst >> BKT_SHIFT;
            int pos = atomicAdd(&base[b], 1);
            packed[pos] = ((dst & 511) << 17) | src;
        }
    }
}

// ---------------- fused per-bucket: node hist + indptr + dinv + scatter ----------------
__global__ __launch_bounds__(256) void fine_kernel(const int* __restrict__ packed,
                                                   const int* __restrict__ bucketBase,
                                                   const int* __restrict__ bucketCnt,
                                                   int* __restrict__ csr_row,
                                                   int* __restrict__ indptr,
                                                   float* __restrict__ dinv, int N) {
    __shared__ int cnt[512];
    __shared__ int pre[512];
    __shared__ int fill[512];
    __shared__ int sm[256];
    int b = blockIdx.x;
    int t = threadIdx.x;
    int d0 = b << BKT_SHIFT;
    int nd = N - d0;
    if (nd > 512) nd = 512;
    cnt[t] = 0; cnt[t + 256] = 0;
    fill[t] = 0; fill[t + 256] = 0;
    __syncthreads();
    int beg = bucketBase[b];
    int end = beg + bucketCnt[b];
    for (int e = beg + t; e < end; e += 256)
        atomicAdd(&cnt[((unsigned)packed[e]) >> 17], 1);
    __syncthreads();
    int c0 = cnt[2 * t], c1 = cnt[2 * t + 1];
    int s = c0 + c1;
    sm[t] = s;
    __syncthreads();
    for (int off = 1; off < 256; off <<= 1) {
        int add = 0;
        if (t >= off) add = sm[t - off];
        __syncthreads();
        if (t >= off) sm[t] += add;
        __syncthreads();
    }
    int ex = sm[t] - s;
    pre[2 * t] = ex;
    pre[2 * t + 1] = ex + c0;
    __syncthreads();
    for (int dl = t; dl < nd; dl += 256) {
        indptr[d0 + dl] = beg + pre[dl];
        dinv[d0 + dl] = rsqrtf((float)(cnt[dl] + 1));
    }
    for (int e = beg + t; e < end; e += 256) {
        unsigned p = (unsigned)packed[e];
        int dl = (int)(p >> 17);
        int src = (int)(p & 0x1FFFFu);
        int pos = beg + pre[dl] + atomicAdd(&fill[dl], 1);
        csr_row[pos] = src;
    }
}

// ---------------- weight prep ----------------
__global__ __launch_bounds__(256) void prep_w1_kernel(const float* __restrict__ W1,
                                                      unsigned short* __restrict__ w1p) {
    int idx = blockIdx.x * 256 + threadIdx.x;
    int q = idx >> 14;
    int rem = idx & 16383;
    int c = rem >> 6, j = rem & 63;
    w1p[idx] = f2bf(W1[(size_t)(q * 64 + j) * HID_DIM + c]);
}

__global__ __launch_bounds__(256) void prep_w2_kernel(const float* __restrict__ W2,
                                                      unsigned short* __restrict__ w2p) {
    int idx = blockIdx.x * 256 + threadIdx.x;
    int c = idx >> 8, k = idx & 255;
    w2p[idx] = f2bf(W2[(size_t)k * OUT_DIM + c]);
}

// ---------------- MFMA MLP: 8-wave/512-thread, depth-2 x prefetch ----------------
// r23 restructure: wave (wr=w&3, wc=w>>2) owns rows[16wr..+16) x cols[128wc..+128)
// -> acc = 8 tiles (32 VGPR), freeing room for depth-2 x prefetch under the
// 128-VGPR cap of __launch_bounds__(512,4) = 2 blocks/CU = 16 waves/CU (vs 12).
// Addresses all 3 prior MLP failure modes: r7 spill (acc halved), r11 occupancy
// (16 waves), r13 depth-2-doesn't-fit (32+32 prefetch+acc fits).
struct __align__(16) MlpSmem {
    union {
        struct {
            unsigned short xs[64][72];     // 9216 B
            unsigned short ws[256][72];    // 36864 B
        } p1;                              // 46080 B
        struct {
            unsigned short hid[64][264];   // 33792 B
            unsigned short w2s[64][264];   // 33792 B (full 64 outcols)
        } p2;                              // 67584 B LDS -> 2 blocks/CU (135KB)
    };
};

__device__ __forceinline__ float4 ldx512(const float* __restrict__ x, int row0, int N,
                                         int t, int i, int q) {
    int e = t * 4 + i * 2048;
    int r = e >> 6, j = e & 63;
    if (row0 + r < N) return *(const float4*)&x[(size_t)(row0 + r) * IN_DIM + q * 64 + j];
    return make_float4(0.f, 0.f, 0.f, 0.f);
}

__global__ __launch_bounds__(512, 4) void mlp_mfma_kernel(const float* __restrict__ x,
                                                          const unsigned short* __restrict__ w1p,
                                                          const float* __restrict__ b1,
                                                          const unsigned short* __restrict__ w2p,
                                                          const float* __restrict__ b2,
                                                          const float* __restrict__ dinv,
                                                          unsigned short* __restrict__ zb,
                                                          unsigned char* __restrict__ hs,
                                                          int N) {
    __shared__ MlpSmem sm;
    int t = threadIdx.x;
    int w = t >> 6, l = t & 63;
    int l15 = l & 15, l4 = l >> 4;
    int wr0 = (w & 3) * 16;     // row group
    int wc = w >> 2;            // col half (GEMM1) / outcol half (GEMM2)
    int row0 = blockIdx.x * 64;

    f32x4 acc[8];
#pragma unroll
    for (int i = 0; i < 8; ++i) acc[i] = (f32x4){0.f, 0.f, 0.f, 0.f};

    float4 xa0, xa1, xb0, xb1;                  // depth-2 x prefetch (2 sets)
    uint4 wv0, wv1, wv2, wv3;                   // depth-1 W1 prefetch

#define LOADXA(q) do { xa0 = ldx512(x, row0, N, t, 0, (q)); xa1 = ldx512(x, row0, N, t, 1, (q)); } while (0)
#define LOADXB(q) do { xb0 = ldx512(x, row0, N, t, 0, (q)); xb1 = ldx512(x, row0, N, t, 1, (q)); } while (0)
#define LOADW(q) do { \
        const unsigned short* _s = w1p + (q) * 16384; \
        wv0 = *(const uint4*)&_s[t * 8 + 0 * 4096]; \
        wv1 = *(const uint4*)&_s[t * 8 + 1 * 4096]; \
        wv2 = *(const uint4*)&_s[t * 8 + 2 * 4096]; \
        wv3 = *(const uint4*)&_s[t * 8 + 3 * 4096]; \
    } while (0)
#define STX1(i, v) do { \
        int e = t * 4 + (i) * 2048; \
        int r = e >> 6, j = e & 63; \
        unsigned u0 = (unsigned)f2bf((v).x) | ((unsigned)f2bf((v).y) << 16); \
        unsigned u1 = (unsigned)f2bf((v).z) | ((unsigned)f2bf((v).w) << 16); \
        *(uint2*)&sm.p1.xs[r][j] = make_uint2(u0, u1); \
    } while (0)
#define STW1(i, v) do { \
        int e = t * 8 + (i) * 4096; \
        int c = e >> 6, j = e & 63; \
        *(uint4*)&sm.p1.ws[c][j] = (v); \
    } while (0)
#define MFMA_CHUNK() do { \
        _Pragma("unroll") \
        for (int s = 0; s < 2; ++s) { \
            short8v a = *(const short8v*)&sm.p1.xs[wr0 + l15][s * 32 + l4 * 8]; \
            _Pragma("unroll") \
            for (int tc = 0; tc < 8; ++tc) { \
                short8v b = *(const short8v*)&sm.p1.ws[wc * 128 + tc * 16 + l15][s * 32 + l4 * 8]; \
                acc[tc] = __builtin_amdgcn_mfma_f32_16x16x32_bf16(a, b, acc[tc], 0, 0, 0); \
            } \
        } \
    } while (0)

    LOADXA(0);
    LOADXB(1);
    LOADW(0);

#pragma unroll
    for (int q = 0; q < 8; q += 2) {
        __syncthreads();
        STX1(0, xa0); STX1(1, xa1);
        STW1(0, wv0); STW1(1, wv1); STW1(2, wv2); STW1(3, wv3);
        __syncthreads();
        if (q + 2 < 8) LOADXA(q + 2);
        LOADW(q + 1);
        MFMA_CHUNK();
        __syncthreads();
        STX1(0, xb0); STX1(1, xb1);
        STW1(0, wv0); STW1(1, wv1); STW1(2, wv2); STW1(3, wv3);
        __syncthreads();
        if (q + 3 < 8) LOADXB(q + 3);
        if (q + 2 < 8) LOADW(q + 2);
        MFMA_CHUNK();
    }
    __syncthreads();  // p1 dead; p2 overlay begins

    // epilogue1: bias + relu -> hid (wave's 16 rows x 128 cols)
#pragma unroll
    for (int tc = 0; tc < 8; ++tc) {
        float bv = b1[wc * 128 + tc * 16 + l15];
#pragma unroll
        for (int i = 0; i < 4; ++i) {
            float v = fmaxf(acc[tc][i] + bv, 0.f);
            sm.p2.hid[wr0 + l4 * 4 + i][wc * 128 + tc * 16 + l15] = f2bf(v);
        }
    }
    // stage full w2s (64 outcols x 256 k): 4 uint4/thread
#pragma unroll
    for (int i = 0; i < 4; ++i) {
        int e = t * 8 + i * 4096;
        int c = e >> 8, k = e & 255;
        *(uint4*)&sm.p2.w2s[c][k] = *(const uint4*)&w2p[e];
    }
    __syncthreads();

    // GEMM2: wave's 16 rows x outcols [wc*32 .. +32), K=256
    f32x4 acc2[2];
#pragma unroll
    for (int i = 0; i < 2; ++i) acc2[i] = (f32x4){0.f, 0.f, 0.f, 0.f};
#pragma unroll
    for (int s = 0; s < 8; ++s) {
        short8v a = *(const short8v*)&sm.p2.hid[wr0 + l15][s * 32 + l4 * 8];
#pragma unroll
        for (int tcl = 0; tcl < 2; ++tcl) {
            short8v b = *(const short8v*)&sm.p2.w2s[wc * 32 + tcl * 16 + l15][s * 32 + l4 * 8];
            acc2[tcl] = __builtin_amdgcn_mfma_f32_16x16x32_bf16(a, b, acc2[tcl], 0, 0, 0);
        }
    }

    // epilogue2: zb = bf16(ALPHA*v), hs = fp8_e4m3(dinv*v)
#pragma unroll
    for (int i = 0; i < 4; ++i) {
        int row = row0 + wr0 + l4 * 4 + i;
        if (row < N) {
            float dv = dinv[row];
#pragma unroll
            for (int tcl = 0; tcl < 2; ++tcl) {
                int col = wc * 32 + tcl * 16 + l15;
                float v = acc2[tcl][i] + b2[col];
                zb[(size_t)row * OUT_DIM + col] = f2bf(ALPHA * v);
                float sv = dv * v;
                int pk = __builtin_amdgcn_cvt_pk_fp8_f32(sv, sv, 0, false);
                hs[(size_t)row * OUT_DIM + col] = (unsigned char)(pk & 0xFF);
            }
        }
    }
#undef LOADXA
#undef LOADXB
#undef LOADW
#undef STX1
#undef STW1
#undef MFMA_CHUNK
}

// ---------------- propagation, fp8 rows, 8-lane/row (r19 structure) + bf16 z-term ----
__global__ __launch_bounds__(256) void prop_fp8_kernel(const unsigned char* __restrict__ hs,
                                                       const unsigned short* __restrict__ zb,
                                                       const float* __restrict__ dinv,
                                                       const int* __restrict__ csr_row,
                                                       const int* __restrict__ indptr,
                                                       unsigned char* __restrict__ hs_out,
                                                       float* __restrict__ hfin,
                                                       int last, int N) {
    int node = blockIdx.x * 4 + (threadIdx.x >> 6);
    if (node >= N) return;
    int l = threadIdx.x & 63;
    int q8 = l >> 3, lf8 = l & 7;
    const uint2* H2 = (const uint2*)hs;   // [N][8] uint2
    int beg = indptr[node], end = indptr[node + 1];
    float b0 = 0.f, b1v = 0.f, b2v = 0.f, b3 = 0.f;
    float b4 = 0.f, b5 = 0.f, b6 = 0.f, b7 = 0.f;
#define ACCU2(u2) do { \
        f32x2 _p0 = __builtin_amdgcn_cvt_pk_f32_fp8((int)(u2).x, false); \
        f32x2 _p1 = __builtin_amdgcn_cvt_pk_f32_fp8((int)(u2).x, true);  \
        f32x2 _p2 = __builtin_amdgcn_cvt_pk_f32_fp8((int)(u2).y, false); \
        f32x2 _p3 = __builtin_amdgcn_cvt_pk_f32_fp8((int)(u2).y, true);  \
        b0 += _p0[0]; b1v += _p0[1]; b2v += _p1[0]; b3 += _p1[1];        \
        b4 += _p2[0]; b5 += _p2[1]; b6 += _p3[0]; b7 += _p3[1];          \
    } while (0)
    int e = beg;
    for (; e + 32 <= end; e += 32) {   // 32 edges: 4 idx loads, 4 gathers (32 rows in flight)
        int r0 = csr_row[e + 0 + q8];
        int r1 = csr_row[e + 8 + q8];
        int r2 = csr_row[e + 16 + q8];
        int r3 = csr_row[e + 24 + q8];
        uint2 u0 = H2[(size_t)r0 * 8 + lf8];
        uint2 u1 = H2[(size_t)r1 * 8 + lf8];
        uint2 u2 = H2[(size_t)r2 * 8 + lf8];
        uint2 u3 = H2[(size_t)r3 * 8 + lf8];
        ACCU2(u0); ACCU2(u1); ACCU2(u2); ACCU2(u3);
    }
    for (; e + 8 <= end; e += 8) {
        int r = csr_row[e + q8];
        uint2 u = H2[(size_t)r * 8 + lf8];
        ACCU2(u);
    }
    if (e + q8 < end) {  // masked tail (<8 edges)
        int r = csr_row[e + q8];
        uint2 u = H2[(size_t)r * 8 + lf8];
        ACCU2(u);
    }
    // reduce across the 8 edge-slots (lane bits 3,4,5)
    b0 += __shfl_xor(b0, 8);  b1v += __shfl_xor(b1v, 8);
    b2v += __shfl_xor(b2v, 8); b3 += __shfl_xor(b3, 8);
    b4 += __shfl_xor(b4, 8);  b5 += __shfl_xor(b5, 8);
    b6 += __shfl_xor(b6, 8);  b7 += __shfl_xor(b7, 8);
    b0 += __shfl_xor(b0, 16); b1v += __shfl_xor(b1v, 16);
    b2v += __shfl_xor(b2v, 16); b3 += __shfl_xor(b3, 16);
    b4 += __shfl_xor(b4, 16); b5 += __shfl_xor(b5, 16);
    b6 += __shfl_xor(b6, 16); b7 += __shfl_xor(b7, 16);
    b0 += __shfl_xor(b0, 32); b1v += __shfl_xor(b1v, 32);
    b2v += __shfl_xor(b2v, 32); b3 += __shfl_xor(b3, 32);
    b4 += __shfl_xor(b4, 32); b5 += __shfl_xor(b5, 32);
    b6 += __shfl_xor(b6, 32); b7 += __shfl_xor(b7, 32);
    {
        uint2 us = H2[(size_t)node * 8 + lf8];  // self loop (post-reduce, uniform)
        ACCU2(us);
    }
#undef ACCU2
    float dcn = dinv[node];
    uint4 zv = ((const uint4*)zb)[(size_t)node * 8 + lf8];
    float o0 = (1.0f - ALPHA) * (dcn * b0) + bflo(zv.x);
    float o1 = (1.0f - ALPHA) * (dcn * b1v) + bfhi(zv.x);
    float o2 = (1.0f - ALPHA) * (dcn * b2v) + bflo(zv.y);
    float o3 = (1.0f - ALPHA) * (dcn * b3) + bfhi(zv.y);
    float o4 = (1.0f - ALPHA) * (dcn * b4) + bflo(zv.z);
    float o5 = (1.0f - ALPHA) * (dcn * b5) + bfhi(zv.z);
    float o6 = (1.0f - ALPHA) * (dcn * b6) + bflo(zv.w);
    float o7 = (1.0f - ALPHA) * (dcn * b7) + bfhi(zv.w);
    if (last) {
        float m = fmaxf(fmaxf(fmaxf(o0, o1), fmaxf(o2, o3)),
                        fmaxf(fmaxf(o4, o5), fmaxf(o6, o7)));
        m = fmaxf(m, __shfl_xor(m, 1));
        m = fmaxf(m, __shfl_xor(m, 2));
        m = fmaxf(m, __shfl_xor(m, 4));
        float s = expf(o0 - m) + expf(o1 - m) + expf(o2 - m) + expf(o3 - m) +
                  expf(o4 - m) + expf(o5 - m) + expf(o6 - m) + expf(o7 - m);
        s += __shfl_xor(s, 1);
        s += __shfl_xor(s, 2);
        s += __shfl_xor(s, 4);
        float lg = logf(s);
        if (q8 == 0) {
            float4 oa, ob;
            oa.x = o0 - m - lg; oa.y = o1 - m - lg; oa.z = o2 - m - lg; oa.w = o3 - m - lg;
            ob.x = o4 - m - lg; ob.y = o5 - m - lg; ob.z = o6 - m - lg; ob.w = o7 - m - lg;
            *(float4*)&hfin[(size_t)node * 64 + lf8 * 8] = oa;
            *(float4*)&hfin[(size_t)node * 64 + lf8 * 8 + 4] = ob;
        }
    } else if (q8 == 0) {
        int pk0 = __builtin_amdgcn_cvt_pk_fp8_f32(dcn * o0, dcn * o1, 0, false);
        pk0 = __builtin_amdgcn_cvt_pk_fp8_f32(dcn * o2, dcn * o3, pk0, true);
        int pk1 = __builtin_amdgcn_cvt_pk_fp8_f32(dcn * o4, dcn * o5, 0, false);
        pk1 = __builtin_amdgcn_cvt_pk_fp8_f32(dcn * o6, dcn * o7, pk1, true);
        ((uint2*)hs_out)[(size_t)node * 8 + lf8] = make_uint2((unsigned)pk0, (unsigned)pk1);
    }
}

extern "C" void kernel_launch(void* const* d_in, const int* in_sizes, int n_in,
                              void* d_out, int out_size, void* d_ws, size_t ws_size,
                              hipStream_t stream) {
    const float* x  = (const float*)d_in[0];
    const int*   ei = (const int*)d_in[1];
    const float* W1 = (const float*)d_in[2];
    const float* b1 = (const float*)d_in[3];
    const float* W2 = (const float*)d_in[4];
    const float* b2 = (const float*)d_in[5];
    float* out = (float*)d_out;
    int N = in_sizes[0] / IN_DIM;
    int E = in_sizes[1] / 2;
    int nbkt = (N + 511) >> BKT_SHIFT;

    char* ws = (char*)d_ws;
    size_t off = 0;
    auto alloc = [&](size_t bytes) -> void* {
        void* p = ws + off;
        off += (bytes + 255) & ~(size_t)255;
        return p;
    };
    unsigned short* zb = (unsigned short*)alloc((size_t)N * OUT_DIM * 2);  // bf16 ALPHA*h0
    float* dinv   = (float*)alloc((size_t)N * 4);
    int*   indptr = (int*)alloc((size_t)(N + 1) * 4);
    int*   bcnt   = (int*)alloc(256 * 4);
    int*   bbase  = (int*)alloc(256 * 4);
    int*   bfill  = (int*)alloc(256 * 4);
    int*   packed = (int*)alloc((size_t)E * 4);
    int*   csr_row= (int*)alloc((size_t)E * 4);
    unsigned short* w1p = (unsigned short*)alloc((size_t)IN_DIM * HID_DIM * 2);
    unsigned short* w2p = (unsigned short*)alloc((size_t)HID_DIM * OUT_DIM * 2);
    unsigned char* hsA = (unsigned char*)alloc((size_t)N * OUT_DIM);  // fp8
    unsigned char* hsB = (unsigned char*)alloc((size_t)N * OUT_DIM);  // fp8
    (void)ws_size; (void)n_in; (void)out_size;

    hipMemsetAsync(bcnt, 0, 256 * 4, stream);

    prep_w1_kernel<<<(IN_DIM * HID_DIM) / 256, 256, 0, stream>>>(W1, w1p);
    prep_w2_kernel<<<(HID_DIM * OUT_DIM) / 256, 256, 0, stream>>>(W2, w2p);

    int pgrid = (E + PART_EPB - 1) / PART_EPB;
    bucket_count_kernel<<<pgrid, 256, 0, stream>>>(ei, E, bcnt);
    bucket_scan_kernel<<<1, 256, 0, stream>>>(bcnt, bbase, bfill, indptr, E, N);
    partition_kernel<<<pgrid, 256, 0, stream>>>(ei, E, bfill, packed);
    fine_kernel<<<nbkt, 256, 0, stream>>>(packed, bbase, bcnt, csr_row, indptr, dinv, N);

    mlp_mfma_kernel<<<(N + 63) / 64, 512, 0, stream>>>(x, w1p, b1, w2p, b2, dinv,
                                                       zb, hsA, N);

    int pb = (N + 3) / 4;
    for (int it = 0; it < KPROP; ++it) {
        const unsigned char* hin = (it % 2 == 0) ? hsA : hsB;
        unsigned char* hout = (it % 2 == 0) ? hsB : hsA;
        int last = (it == KPROP - 1) ? 1 : 0;
        prop_fp8_kernel<<<pb, 256, 0, stream>>>(hin, zb, dinv, csr_row, indptr,
                                                hout, out, last, N);
    }
}